// Round 1
// baseline (1846.701 us; speedup 1.0000x reference)
//
#include <hip/hip_runtime.h>
#include <math.h>

// Problem dims
#define B_   32
#define CIN  32
#define V_   512
#define L_   64
#define E_   10
#define COUT 64
#define CCAT 128

// workspace float offsets
#define OFF_N1T  0          // 3*512*10
#define OFF_T2   15360      // 3*512*10
#define OFF_WT   30720      // 128*64 (mlp_w transposed [k][o])
#define OFF_A1   38912      // 512*512
#define OFF_A2   301056     // 512*512
#define OFF_PST  563200     // 512*1536  Pstack[v][w'] : cols 0-511=P1, 512-1023=P2, 1024-1535=P3
#define OFF_Y    1349632    // chunkN*32*1536*64

// ---------------------------------------------------------------------------
// Kernel 1: node-vector hop transforms + mlp_w transpose (tiny, 1 block)
// ---------------------------------------------------------------------------
__global__ __launch_bounds__(256) void transform_kernel(
    const float* __restrict__ nv1, const float* __restrict__ nv2,
    const float* __restrict__ wtr, const float* __restrict__ btr,
    const float* __restrict__ mlpw, float* __restrict__ ws)
{
    float* n1t = ws + OFF_N1T;   // [3][512][10]
    float* t2  = ws + OFF_T2;    // [3][512][10]  (t2[h][w][e] = n2_h[e][w])
    float* WT  = ws + OFF_WT;    // [128][64]
    int t = threadIdx.x;
    for (int j = t; j < 5120; j += 256) {
        int v = j / 10, e = j % 10;
        n1t[j]        = nv1[j];
        t2[v*10 + e]  = nv2[e*512 + v];
    }
    for (int j = t; j < 8192; j += 256) {
        int k = j / 64, o = j % 64;
        WT[j] = mlpw[o*128 + k];
    }
    __syncthreads();
    for (int h = 1; h <= 2; ++h) {
        const float* w = wtr + (h-1)*100;   // [10][10] row-major [f][e]
        const float* b = btr + (h-1)*10;
        for (int j = t; j < 5120; j += 256) {
            int v = j / 10, e = j % 10;
            float s1 = b[e], s2 = b[e];
            #pragma unroll
            for (int f = 0; f < 10; ++f) {
                s1 += n1t[(h-1)*5120 + v*10 + f] * w[f*10 + e];
                s2 += t2 [(h-1)*5120 + v*10 + f] * w[f*10 + e];
            }
            n1t[h*5120 + j] = s1;
            t2 [h*5120 + j] = s2;
        }
        __syncthreads();
    }
}

// ---------------------------------------------------------------------------
// Kernel 2: adjacency rows: relu + row-softmax.  grid (512, 3)
//   k=0 -> Pstack cols 0-511 (P1=A0); k=1 -> A1 temp; k=2 -> A2 temp
// ---------------------------------------------------------------------------
__global__ __launch_bounds__(256) void adj_kernel(float* __restrict__ ws)
{
    int v = blockIdx.x, k = blockIdx.y;
    const float* n1v = ws + OFF_N1T + ((size_t)k*512 + v)*10;
    const float* t2b = ws + OFF_T2  + (size_t)k*5120;
    float n1r[10];
    #pragma unroll
    for (int e = 0; e < 10; ++e) n1r[e] = n1v[e];

    int t = threadIdx.x;
    float s[2];
    #pragma unroll
    for (int ii = 0; ii < 2; ++ii) {
        int w = t + ii*256;
        const float* t2w = t2b + w*10;
        float d = 0.f;
        #pragma unroll
        for (int e = 0; e < 10; ++e) d += n1r[e] * t2w[e];
        s[ii] = d > 0.f ? d : 0.f;
    }
    __shared__ float red[256];
    float m = fmaxf(s[0], s[1]);
    red[t] = m; __syncthreads();
    for (int off = 128; off > 0; off >>= 1) {
        if (t < off) red[t] = fmaxf(red[t], red[t+off]);
        __syncthreads();
    }
    float mx = red[0];
    __syncthreads();
    float e0 = expf(s[0]-mx), e1 = expf(s[1]-mx);
    red[t] = e0 + e1; __syncthreads();
    for (int off = 128; off > 0; off >>= 1) {
        if (t < off) red[t] += red[t+off];
        __syncthreads();
    }
    float inv = 1.f / red[0];

    float* dst;
    if (k == 0)      dst = ws + OFF_PST + (size_t)v*1536;
    else if (k == 1) dst = ws + OFF_A1  + (size_t)v*512;
    else             dst = ws + OFF_A2  + (size_t)v*512;
    dst[t]       = e0 * inv;
    dst[t + 256] = e1 * inv;
}

// ---------------------------------------------------------------------------
// Kernel 3: small 512x512x512 matmul  C[v][w] = sum_u A[v][u]*B[u][w]
// ---------------------------------------------------------------------------
__global__ __launch_bounds__(256) void chain_kernel(
    const float* __restrict__ A, int lda,
    const float* __restrict__ Bm, int ldb,
    float* __restrict__ C, int ldc)
{
    __shared__ float At[16][64];   // At[u][vv]
    __shared__ float Bt[16][64];   // Bt[u][ww]
    int tx = threadIdx.x % 16, ty = threadIdx.x / 16;
    int v0 = blockIdx.y * 64, w0 = blockIdx.x * 64;
    float acc[4][4] = {};
    for (int u0 = 0; u0 < 512; u0 += 16) {
        __syncthreads();
        #pragma unroll
        for (int i = 0; i < 4; ++i) {
            int j = threadIdx.x + i*256;
            int vv = j / 16, u = j % 16;
            At[u][vv] = A[(size_t)(v0+vv)*lda + u0 + u];
            int u2 = j / 64, ww = j % 64;
            Bt[u2][ww] = Bm[(size_t)(u0+u2)*ldb + w0 + ww];
        }
        __syncthreads();
        #pragma unroll
        for (int u = 0; u < 16; ++u) {
            float a[4], b[4];
            #pragma unroll
            for (int i = 0; i < 4; ++i) a[i] = At[u][ty*4+i];
            #pragma unroll
            for (int j = 0; j < 4; ++j) b[j] = Bt[u][tx*4+j];
            #pragma unroll
            for (int i = 0; i < 4; ++i)
                #pragma unroll
                for (int j = 0; j < 4; ++j)
                    acc[i][j] += a[i]*b[j];
        }
    }
    #pragma unroll
    for (int i = 0; i < 4; ++i)
        #pragma unroll
        for (int j = 0; j < 4; ++j)
            C[(size_t)(v0+ty*4+i)*ldc + w0+tx*4+j] = acc[i][j];
}

// ---------------------------------------------------------------------------
// Kernel 4: batched stacked GEMM.  Per batch (n,c): Y[w'][l] = sum_v Pstack[v][w']*X[v][l]
//   grid: x = 12 w'-tiles of 128, y = batches in chunk.  block 256.
// ---------------------------------------------------------------------------
__global__ __launch_bounds__(256) void gemm_kernel(
    const float* __restrict__ x, const float* __restrict__ Pst,
    float* __restrict__ Y, int n0)
{
    const float* X  = x + ((size_t)n0*32 + blockIdx.y) * (512*64);
    float*       Yb = Y + (size_t)blockIdx.y*1536*64 + (size_t)blockIdx.x*128*64;
    const float* P  = Pst + blockIdx.x*128;

    __shared__ __align__(16) float Pt[32*128];  // [v][w] 16 KB
    __shared__ __align__(16) float Xt[32*64];   // [v][l]  8 KB

    int t  = threadIdx.x;
    int tl = t % 16, tw = t / 16;      // l-group (4 l), w-group (8 w)
    float acc[8][4] = {};

    for (int v0 = 0; v0 < 512; v0 += 32) {
        __syncthreads();
        #pragma unroll
        for (int i = 0; i < 4; ++i) {
            int j = t + i*256;               // float4 id, 0..1023
            int v = j / 32, wq = j % 32;
            *(float4*)&Pt[v*128 + wq*4] = *(const float4*)&P[(size_t)(v0+v)*1536 + wq*4];
        }
        #pragma unroll
        for (int i = 0; i < 2; ++i) {
            int j = t + i*256;               // 0..511
            int v = j / 16, lq = j % 16;
            *(float4*)&Xt[v*64 + lq*4] = *(const float4*)&X[(size_t)(v0+v)*64 + lq*4];
        }
        __syncthreads();
        #pragma unroll
        for (int v = 0; v < 32; ++v) {
            float4 p0 = *(float4*)&Pt[v*128 + tw*8];
            float4 p1 = *(float4*)&Pt[v*128 + tw*8 + 4];
            float4 xv = *(float4*)&Xt[v*64 + tl*4];
            float p[8]  = {p0.x,p0.y,p0.z,p0.w,p1.x,p1.y,p1.z,p1.w};
            float xx[4] = {xv.x,xv.y,xv.z,xv.w};
            #pragma unroll
            for (int i = 0; i < 8; ++i)
                #pragma unroll
                for (int j = 0; j < 4; ++j)
                    acc[i][j] += p[i]*xx[j];
        }
    }
    #pragma unroll
    for (int i = 0; i < 8; ++i) {
        float4 o = {acc[i][0], acc[i][1], acc[i][2], acc[i][3]};
        *(float4*)&Yb[(size_t)(tw*8+i)*64 + tl*4] = o;
    }
}

// ---------------------------------------------------------------------------
// Kernel 5: combine / 1x1 conv.  grid (512 w, chunkN).  block 256.
//   out[n,o,w,l] = b[o] + sum_c W[o,c]x + W[o,32+c]Y1[l] + W[o,64+c]Y2[l-1] + W[o,96+c]Y3[l-3]
// ---------------------------------------------------------------------------
__global__ __launch_bounds__(256) void combine_kernel(
    const float* __restrict__ x, const float* __restrict__ Y,
    const float* __restrict__ WT, const float* __restrict__ bias,
    float* __restrict__ out, int n0)
{
    int w  = blockIdx.x;
    int cn = blockIdx.y;
    int n  = n0 + cn;
    __shared__ __align__(16) float Hs[128*64];   // 32 KB
    __shared__ __align__(16) float Ws[128*64];   // 32 KB  [k][o]
    int t = threadIdx.x;

    #pragma unroll
    for (int i = 0; i < 8; ++i) {
        int j = (t + i*256)*4;
        *(float4*)&Ws[j] = *(const float4*)&WT[j];
    }
    // rows 0..31 = x ; rows 32..63 = Y1 (unshifted)
    #pragma unroll
    for (int i = 0; i < 2; ++i) {
        int j = t + i*256;                    // 0..511 float4 ids
        int c = j / 16, lq = j % 16;
        *(float4*)&Hs[c*64 + lq*4] =
            *(const float4*)&x[(((size_t)n*32 + c)*512 + w)*64 + lq*4];
        *(float4*)&Hs[(32+c)*64 + lq*4] =
            *(const float4*)&Y[(((size_t)cn*32 + c)*1536 + w)*64 + lq*4];
    }
    // rows 64..95 = Y2 shifted by 1 ; rows 96..127 = Y3 shifted by 3
    #pragma unroll
    for (int i = 0; i < 8; ++i) {
        int j = t + i*256;                    // 0..2047
        int c = j / 64, l = j % 64;
        float v2 = (l >= 1) ? Y[(((size_t)cn*32 + c)*1536 + 512  + w)*64 + (l-1)] : 0.f;
        float v3 = (l >= 3) ? Y[(((size_t)cn*32 + c)*1536 + 1024 + w)*64 + (l-3)] : 0.f;
        Hs[(64+c)*64 + l] = v2;
        Hs[(96+c)*64 + l] = v3;
    }
    __syncthreads();

    int lg = t % 16, og = t / 16;
    int o0 = og*4, l0 = lg*4;
    float acc[4][4];
    #pragma unroll
    for (int i = 0; i < 4; ++i) {
        float bv = bias[o0+i];
        #pragma unroll
        for (int j = 0; j < 4; ++j) acc[i][j] = bv;
    }
    #pragma unroll 4
    for (int k = 0; k < 128; ++k) {
        float4 wv = *(float4*)&Ws[k*64 + o0];
        float4 hv = *(float4*)&Hs[k*64 + l0];
        float wa[4] = {wv.x,wv.y,wv.z,wv.w};
        float ha[4] = {hv.x,hv.y,hv.z,hv.w};
        #pragma unroll
        for (int i = 0; i < 4; ++i)
            #pragma unroll
            for (int j = 0; j < 4; ++j)
                acc[i][j] += wa[i]*ha[j];
    }
    #pragma unroll
    for (int i = 0; i < 4; ++i) {
        float4 o = {acc[i][0], acc[i][1], acc[i][2], acc[i][3]};
        *(float4*)&out[(((size_t)n*64 + o0+i)*512 + w)*64 + l0] = o;
    }
}

// ---------------------------------------------------------------------------
extern "C" void kernel_launch(void* const* d_in, const int* in_sizes, int n_in,
                              void* d_out, int out_size, void* d_ws, size_t ws_size,
                              hipStream_t stream) {
    const float* x    = (const float*)d_in[0];
    const float* nv1  = (const float*)d_in[1];
    const float* nv2  = (const float*)d_in[2];
    const float* wtr  = (const float*)d_in[3];
    const float* btr  = (const float*)d_in[4];
    const float* mlpw = (const float*)d_in[5];
    const float* mlpb = (const float*)d_in[6];
    float* out = (float*)d_out;
    float* ws  = (float*)d_ws;

    transform_kernel<<<1, 256, 0, stream>>>(nv1, nv2, wtr, btr, mlpw, ws);
    adj_kernel<<<dim3(512, 3), 256, 0, stream>>>(ws);
    // P2 = A0 @ A1 ; P3 = P2 @ A2
    chain_kernel<<<dim3(8, 8), 256, 0, stream>>>(ws+OFF_PST,      1536, ws+OFF_A1, 512, ws+OFF_PST+512,  1536);
    chain_kernel<<<dim3(8, 8), 256, 0, stream>>>(ws+OFF_PST+512,  1536, ws+OFF_A2, 512, ws+OFF_PST+1024, 1536);

    // choose batch chunking so Y fits in workspace (deterministic: ws_size constant)
    size_t ws_f  = ws_size / 4;
    size_t avail = ws_f > OFF_Y ? ws_f - OFF_Y : 0;
    size_t per_n = 32UL * 1536 * 64;
    int chunk = 32;
    while (chunk > 1 && (size_t)chunk * per_n > avail) chunk >>= 1;

    for (int n0 = 0; n0 < 32; n0 += chunk) {
        gemm_kernel<<<dim3(12, chunk*32), 256, 0, stream>>>(x, ws+OFF_PST, ws+OFF_Y, n0);
        combine_kernel<<<dim3(512, chunk), 256, 0, stream>>>(x, ws+OFF_Y, ws+OFF_WT, mlpb, out, n0);
    }
}

// Round 2
// 1188.639 us; speedup vs baseline: 1.5536x; 1.5536x over previous
//
#include <hip/hip_runtime.h>
#include <math.h>

typedef unsigned int uint;
typedef unsigned short ushort;

// Problem dims
#define B_   32
#define CIN  32
#define V_   512
#define L_   64
#define COUT 64

// workspace float offsets
#define OFF_N1T  0          // 3*512*10
#define OFF_T2   15360      // 3*512*10
#define OFF_WT   30720      // 128*64 (mlp_w transposed [k][o])
#define OFF_A1   38912      // 512*512
#define OFF_A2   301056     // 512*512
#define OFF_PST  563200     // 512*1536  Pstack[v][w'] fp32
#define OFF_PTH  1349632    // 3*512*512 bf16 hi  (= 393216 floats)
#define OFF_PTL  1742848    // 3*512*512 bf16 lo
#define OFF_XTH  2136064    // chunk*32*512*64 bf16 hi, then lo, then Y fp32

typedef __attribute__((ext_vector_type(8))) short bf16x8;
typedef __attribute__((ext_vector_type(4))) float f32x4;

__device__ __forceinline__ ushort f2bf(float f) {
    uint b = __float_as_uint(f);
    b += 0x7fffu + ((b >> 16) & 1u);
    return (ushort)(b >> 16);
}
__device__ __forceinline__ void split_bf(float f, ushort& h, ushort& l) {
    uint b = __float_as_uint(f);
    uint r = b + 0x7fffu + ((b >> 16) & 1u);
    ushort hh = (ushort)(r >> 16);
    h = hh;
    float hf = __uint_as_float((uint)hh << 16);
    l = f2bf(f - hf);
}

// ---------------------------------------------------------------------------
// Kernel 1: node-vector hop transforms + mlp_w transpose (tiny, 1 block)
// ---------------------------------------------------------------------------
__global__ __launch_bounds__(256) void transform_kernel(
    const float* __restrict__ nv1, const float* __restrict__ nv2,
    const float* __restrict__ wtr, const float* __restrict__ btr,
    const float* __restrict__ mlpw, float* __restrict__ ws)
{
    float* n1t = ws + OFF_N1T;   // [3][512][10]
    float* t2  = ws + OFF_T2;    // [3][512][10]
    float* WT  = ws + OFF_WT;    // [128][64]
    int t = threadIdx.x;
    for (int j = t; j < 5120; j += 256) {
        int v = j / 10, e = j % 10;
        n1t[j]        = nv1[j];
        t2[v*10 + e]  = nv2[e*512 + v];
    }
    for (int j = t; j < 8192; j += 256) {
        int k = j / 64, o = j % 64;
        WT[j] = mlpw[o*128 + k];
    }
    __syncthreads();
    for (int h = 1; h <= 2; ++h) {
        const float* w = wtr + (h-1)*100;
        const float* b = btr + (h-1)*10;
        for (int j = t; j < 5120; j += 256) {
            int v = j / 10, e = j % 10;
            float s1 = b[e], s2 = b[e];
            #pragma unroll
            for (int f = 0; f < 10; ++f) {
                s1 += n1t[(h-1)*5120 + v*10 + f] * w[f*10 + e];
                s2 += t2 [(h-1)*5120 + v*10 + f] * w[f*10 + e];
            }
            n1t[h*5120 + j] = s1;
            t2 [h*5120 + j] = s2;
        }
        __syncthreads();
    }
}

// ---------------------------------------------------------------------------
// Kernel 2: adjacency rows: relu + row-softmax.  grid (512, 3)
// ---------------------------------------------------------------------------
__global__ __launch_bounds__(256) void adj_kernel(float* __restrict__ ws)
{
    int v = blockIdx.x, k = blockIdx.y;
    const float* n1v = ws + OFF_N1T + ((size_t)k*512 + v)*10;
    const float* t2b = ws + OFF_T2  + (size_t)k*5120;
    float n1r[10];
    #pragma unroll
    for (int e = 0; e < 10; ++e) n1r[e] = n1v[e];

    int t = threadIdx.x;
    float s[2];
    #pragma unroll
    for (int ii = 0; ii < 2; ++ii) {
        int w = t + ii*256;
        const float* t2w = t2b + w*10;
        float d = 0.f;
        #pragma unroll
        for (int e = 0; e < 10; ++e) d += n1r[e] * t2w[e];
        s[ii] = d > 0.f ? d : 0.f;
    }
    __shared__ float red[256];
    float m = fmaxf(s[0], s[1]);
    red[t] = m; __syncthreads();
    for (int off = 128; off > 0; off >>= 1) {
        if (t < off) red[t] = fmaxf(red[t], red[t+off]);
        __syncthreads();
    }
    float mx = red[0];
    __syncthreads();
    float e0 = expf(s[0]-mx), e1 = expf(s[1]-mx);
    red[t] = e0 + e1; __syncthreads();
    for (int off = 128; off > 0; off >>= 1) {
        if (t < off) red[t] += red[t+off];
        __syncthreads();
    }
    float inv = 1.f / red[0];

    float* dst;
    if (k == 0)      dst = ws + OFF_PST + (size_t)v*1536;
    else if (k == 1) dst = ws + OFF_A1  + (size_t)v*512;
    else             dst = ws + OFF_A2  + (size_t)v*512;
    dst[t]       = e0 * inv;
    dst[t + 256] = e1 * inv;
}

// ---------------------------------------------------------------------------
// Kernel 3: small 512x512x512 matmul  C[v][w] = sum_u A[v][u]*B[u][w]
// ---------------------------------------------------------------------------
__global__ __launch_bounds__(256) void chain_kernel(
    const float* __restrict__ A, int lda,
    const float* __restrict__ Bm, int ldb,
    float* __restrict__ C, int ldc)
{
    __shared__ float At[16][64];
    __shared__ float Bt[16][64];
    int tx = threadIdx.x % 16, ty = threadIdx.x / 16;
    int v0 = blockIdx.y * 64, w0 = blockIdx.x * 64;
    float acc[4][4] = {};
    for (int u0 = 0; u0 < 512; u0 += 16) {
        __syncthreads();
        #pragma unroll
        for (int i = 0; i < 4; ++i) {
            int j = threadIdx.x + i*256;
            int vv = j / 16, u = j % 16;
            At[u][vv] = A[(size_t)(v0+vv)*lda + u0 + u];
            int u2 = j / 64, ww = j % 64;
            Bt[u2][ww] = Bm[(size_t)(u0+u2)*ldb + w0 + ww];
        }
        __syncthreads();
        #pragma unroll
        for (int u = 0; u < 16; ++u) {
            float a[4], b[4];
            #pragma unroll
            for (int i = 0; i < 4; ++i) a[i] = At[u][ty*4+i];
            #pragma unroll
            for (int j = 0; j < 4; ++j) b[j] = Bt[u][tx*4+j];
            #pragma unroll
            for (int i = 0; i < 4; ++i)
                #pragma unroll
                for (int j = 0; j < 4; ++j)
                    acc[i][j] += a[i]*b[j];
        }
    }
    #pragma unroll
    for (int i = 0; i < 4; ++i)
        #pragma unroll
        for (int j = 0; j < 4; ++j)
            C[(size_t)(v0+ty*4+i)*ldc + w0+tx*4+j] = acc[i][j];
}

// ---------------------------------------------------------------------------
// Kernel 3b: transpose + bf16 hi/lo split of Pstack -> PT[hop][w][v]
//   grid (16, 16, 3), block 256
// ---------------------------------------------------------------------------
__global__ __launch_bounds__(256) void ptsplit_kernel(
    const float* __restrict__ Pst, ushort* __restrict__ PTh, ushort* __restrict__ PTl)
{
    int h = blockIdx.z;
    int w0 = blockIdx.x * 32, v0 = blockIdx.y * 32;
    __shared__ float tile[32][33];
    int t = threadIdx.x;
    int tc = t & 31, tr = t >> 5;   // 8 rows per pass
    #pragma unroll
    for (int i = 0; i < 4; ++i) {
        int v = tr + i*8;
        tile[v][tc] = Pst[(size_t)(v0+v)*1536 + h*512 + w0 + tc];
    }
    __syncthreads();
    #pragma unroll
    for (int i = 0; i < 4; ++i) {
        int w = tr + i*8;
        float x = tile[tc][w];
        ushort hh, ll;
        split_bf(x, hh, ll);
        size_t o = ((size_t)h*512 + w0 + w)*512 + v0 + tc;
        PTh[o] = hh;
        PTl[o] = ll;
    }
}

// ---------------------------------------------------------------------------
// Kernel 3c: transpose + split X chunk -> XT[b][l][v]  (bf16 hi/lo)
//   grid (8, chunk*32), block 256
// ---------------------------------------------------------------------------
__global__ __launch_bounds__(256) void xtsplit_kernel(
    const float* __restrict__ x, ushort* __restrict__ XTh, ushort* __restrict__ XTl, int n0)
{
    int cb = blockIdx.y;
    int v0 = blockIdx.x * 64;
    const float* Xb = x + ((size_t)n0*32 + cb)*(512*64);
    __shared__ float tile[64][65];
    int t = threadIdx.x;
    int tl4 = (t & 15) * 4, tv = t >> 4;   // 16 rows per pass
    #pragma unroll
    for (int i = 0; i < 4; ++i) {
        int v = tv + i*16;
        *(float4*)&tile[v][tl4] = *(const float4*)&Xb[(size_t)(v0+v)*64 + tl4];
    }
    __syncthreads();
    #pragma unroll
    for (int i = 0; i < 4; ++i) {
        int l = tv + i*16;
        uint hw[2], lw[2];
        #pragma unroll
        for (int k = 0; k < 2; ++k) {
            ushort h0, l0, h1, l1;
            split_bf(tile[tl4 + 2*k][l],     h0, l0);
            split_bf(tile[tl4 + 2*k + 1][l], h1, l1);
            hw[k] = (uint)h0 | ((uint)h1 << 16);
            lw[k] = (uint)l0 | ((uint)l1 << 16);
        }
        size_t o = ((size_t)cb*64 + l)*512 + v0 + tl4;
        *(uint2*)&XTh[o] = make_uint2(hw[0], hw[1]);
        *(uint2*)&XTl[o] = make_uint2(lw[0], lw[1]);
    }
}

// ---------------------------------------------------------------------------
// Kernel 4: MFMA batched GEMM, 3-term split precision.
//   Y[cb][w'][l] = sum_v PT[w'][v] * XT[cb][l][v]
//   grid (12, chunk*32): x -> hop=bx>>2, wtile=bx&3 (128 rows); block 256 = 4 waves
// ---------------------------------------------------------------------------
__global__ __launch_bounds__(256, 2) void gemm_mfma_kernel(
    const ushort* __restrict__ PTh, const ushort* __restrict__ PTl,
    const ushort* __restrict__ XTh, const ushort* __restrict__ XTl,
    float* __restrict__ Y)
{
    int bx = blockIdx.x;
    int cb = blockIdx.y;
    int hop = bx >> 2, wt = bx & 3;
    const ushort* Ph = PTh + ((size_t)hop*512 + wt*128)*512;
    const ushort* Pl = PTl + ((size_t)hop*512 + wt*128)*512;
    const ushort* Xh = XTh + (size_t)cb*64*512;
    const ushort* Xl = XTl + (size_t)cb*64*512;
    float* Yb = Y + (size_t)cb*(1536*64) + ((size_t)hop*512 + wt*128)*64;

    __shared__ __align__(16) ushort Ah[128*72];
    __shared__ __align__(16) ushort Al[128*72];
    __shared__ __align__(16) ushort Bh[64*72];
    __shared__ __align__(16) ushort Bl[64*72];

    int t = threadIdx.x;
    int wid = t >> 6, lane = t & 63;
    int wm0 = (wid >> 1) * 64;      // wave M offset (w')
    int wn0 = (wid & 1) * 32;       // wave N offset (l)
    int lr = lane & 15;
    int lk = (lane >> 4) * 8;

    f32x4 acc[4][2];
    #pragma unroll
    for (int i = 0; i < 4; ++i)
        #pragma unroll
        for (int j = 0; j < 2; ++j)
            acc[i][j] = (f32x4){0.f, 0.f, 0.f, 0.f};

    for (int v0 = 0; v0 < 512; v0 += 64) {
        __syncthreads();
        // stage A (128x64 bf16 x2): 1024 16B-chunks per buffer
        #pragma unroll
        for (int i = 0; i < 4; ++i) {
            int j = t + i*256;
            int m = j >> 3, c = (j & 7) * 8;
            *(bf16x8*)&Ah[m*72 + c] = *(const bf16x8*)&Ph[(size_t)m*512 + v0 + c];
            *(bf16x8*)&Al[m*72 + c] = *(const bf16x8*)&Pl[(size_t)m*512 + v0 + c];
        }
        // stage B (64x64 bf16 x2): 512 16B-chunks per buffer
        #pragma unroll
        for (int i = 0; i < 2; ++i) {
            int j = t + i*256;
            int l = j >> 3, c = (j & 7) * 8;
            *(bf16x8*)&Bh[l*72 + c] = *(const bf16x8*)&Xh[(size_t)l*512 + v0 + c];
            *(bf16x8*)&Bl[l*72 + c] = *(const bf16x8*)&Xl[(size_t)l*512 + v0 + c];
        }
        __syncthreads();
        #pragma unroll
        for (int kk = 0; kk < 2; ++kk) {
            int ko = kk*32 + lk;
            bf16x8 bh[2], bl[2];
            #pragma unroll
            for (int nf = 0; nf < 2; ++nf) {
                int n = wn0 + nf*16 + lr;
                bh[nf] = *(const bf16x8*)&Bh[n*72 + ko];
                bl[nf] = *(const bf16x8*)&Bl[n*72 + ko];
            }
            #pragma unroll
            for (int mf = 0; mf < 4; ++mf) {
                int m = wm0 + mf*16 + lr;
                bf16x8 ah = *(const bf16x8*)&Ah[m*72 + ko];
                bf16x8 al = *(const bf16x8*)&Al[m*72 + ko];
                #pragma unroll
                for (int nf = 0; nf < 2; ++nf) {
                    acc[mf][nf] = __builtin_amdgcn_mfma_f32_16x16x32_bf16(ah, bh[nf], acc[mf][nf], 0, 0, 0);
                    acc[mf][nf] = __builtin_amdgcn_mfma_f32_16x16x32_bf16(ah, bl[nf], acc[mf][nf], 0, 0, 0);
                    acc[mf][nf] = __builtin_amdgcn_mfma_f32_16x16x32_bf16(al, bh[nf], acc[mf][nf], 0, 0, 0);
                }
            }
        }
    }
    // write C: row = (lane>>4)*4 + r (+16*mf), col = lane&15 (+16*nf)
    int orow = wm0 + (lane >> 4) * 4;
    int ocol = wn0 + lr;
    #pragma unroll
    for (int mf = 0; mf < 4; ++mf)
        #pragma unroll
        for (int nf = 0; nf < 2; ++nf)
            #pragma unroll
            for (int r = 0; r < 4; ++r)
                Yb[(size_t)(orow + mf*16 + r)*64 + ocol + nf*16] = acc[mf][nf][r];
}

// ---------------------------------------------------------------------------
// Kernel 5: combine / 1x1 conv.  grid (512 w, chunkN).  block 256.
// ---------------------------------------------------------------------------
__global__ __launch_bounds__(256) void combine_kernel(
    const float* __restrict__ x, const float* __restrict__ Y,
    const float* __restrict__ WT, const float* __restrict__ bias,
    float* __restrict__ out, int n0)
{
    int w  = blockIdx.x;
    int cn = blockIdx.y;
    int n  = n0 + cn;
    __shared__ __align__(16) float Hs[128*64];
    __shared__ __align__(16) float Ws[128*64];
    int t = threadIdx.x;

    #pragma unroll
    for (int i = 0; i < 8; ++i) {
        int j = (t + i*256)*4;
        *(float4*)&Ws[j] = *(const float4*)&WT[j];
    }
    #pragma unroll
    for (int i = 0; i < 2; ++i) {
        int j = t + i*256;
        int c = j / 16, lq = j % 16;
        *(float4*)&Hs[c*64 + lq*4] =
            *(const float4*)&x[(((size_t)n*32 + c)*512 + w)*64 + lq*4];
        *(float4*)&Hs[(32+c)*64 + lq*4] =
            *(const float4*)&Y[(((size_t)cn*32 + c)*1536 + w)*64 + lq*4];
    }
    #pragma unroll
    for (int i = 0; i < 8; ++i) {
        int j = t + i*256;
        int c = j / 64, l = j % 64;
        float v2 = (l >= 1) ? Y[(((size_t)cn*32 + c)*1536 + 512  + w)*64 + (l-1)] : 0.f;
        float v3 = (l >= 3) ? Y[(((size_t)cn*32 + c)*1536 + 1024 + w)*64 + (l-3)] : 0.f;
        Hs[(64+c)*64 + l] = v2;
        Hs[(96+c)*64 + l] = v3;
    }
    __syncthreads();

    int lg = t % 16, og = t / 16;
    int o0 = og*4, l0 = lg*4;
    float acc[4][4];
    #pragma unroll
    for (int i = 0; i < 4; ++i) {
        float bv = bias[o0+i];
        #pragma unroll
        for (int j = 0; j < 4; ++j) acc[i][j] = bv;
    }
    #pragma unroll 4
    for (int k = 0; k < 128; ++k) {
        float4 wv = *(float4*)&Ws[k*64 + o0];
        float4 hv = *(float4*)&Hs[k*64 + l0];
        float wa[4] = {wv.x,wv.y,wv.z,wv.w};
        float ha[4] = {hv.x,hv.y,hv.z,hv.w};
        #pragma unroll
        for (int i = 0; i < 4; ++i)
            #pragma unroll
            for (int j = 0; j < 4; ++j)
                acc[i][j] += wa[i]*ha[j];
    }
    #pragma unroll
    for (int i = 0; i < 4; ++i) {
        float4 o = {acc[i][0], acc[i][1], acc[i][2], acc[i][3]};
        *(float4*)&out[(((size_t)n*64 + o0+i)*512 + w)*64 + l0] = o;
    }
}

// ---------------------------------------------------------------------------
extern "C" void kernel_launch(void* const* d_in, const int* in_sizes, int n_in,
                              void* d_out, int out_size, void* d_ws, size_t ws_size,
                              hipStream_t stream) {
    const float* x    = (const float*)d_in[0];
    const float* nv1  = (const float*)d_in[1];
    const float* nv2  = (const float*)d_in[2];
    const float* wtr  = (const float*)d_in[3];
    const float* btr  = (const float*)d_in[4];
    const float* mlpw = (const float*)d_in[5];
    const float* mlpb = (const float*)d_in[6];
    float* out = (float*)d_out;
    float* ws  = (float*)d_ws;

    transform_kernel<<<1, 256, 0, stream>>>(nv1, nv2, wtr, btr, mlpw, ws);
    adj_kernel<<<dim3(512, 3), 256, 0, stream>>>(ws);
    // P2 = A0 @ A1 ; P3 = P2 @ A2 (fp32, row-major Pstack)
    chain_kernel<<<dim3(8, 8), 256, 0, stream>>>(ws+OFF_PST,      1536, ws+OFF_A1, 512, ws+OFF_PST+512,  1536);
    chain_kernel<<<dim3(8, 8), 256, 0, stream>>>(ws+OFF_PST+512,  1536, ws+OFF_A2, 512, ws+OFF_PST+1024, 1536);

    ushort* PTh = (ushort*)(ws + OFF_PTH);
    ushort* PTl = (ushort*)(ws + OFF_PTL);
    ptsplit_kernel<<<dim3(16, 16, 3), 256, 0, stream>>>(ws + OFF_PST, PTh, PTl);

    // chunk selection: floats needed = OFF_XTH + chunk*(1048576 + 3145728)
    size_t ws_f = ws_size / 4;
    int chunk = 32;
    while (chunk > 1 && (size_t)OFF_XTH + (size_t)chunk*4194304ull > ws_f) chunk >>= 1;

    ushort* XTh = (ushort*)(ws + OFF_XTH);
    ushort* XTl = (ushort*)(ws + OFF_XTH + (size_t)chunk*524288);
    float*  Yw  = ws + OFF_XTH + (size_t)chunk*1048576;

    for (int n0 = 0; n0 < 32; n0 += chunk) {
        xtsplit_kernel<<<dim3(8, chunk*32), 256, 0, stream>>>(x, XTh, XTl, n0);
        gemm_mfma_kernel<<<dim3(12, chunk*32), 256, 0, stream>>>(PTh, PTl, XTh, XTl, Yw);
        combine_kernel<<<dim3(512, chunk), 256, 0, stream>>>(x, Yw, ws+OFF_WT, mlpb, out, n0);
    }
}

// Round 4
// 928.030 us; speedup vs baseline: 1.9899x; 1.2808x over previous
//
#include <hip/hip_runtime.h>
#include <math.h>

typedef unsigned int uint;
typedef unsigned short ushort;
typedef _Float16 f16;
typedef __attribute__((ext_vector_type(8))) _Float16 f16x8;
typedef __attribute__((ext_vector_type(4))) _Float16 f16x4;
typedef __attribute__((ext_vector_type(4))) float f32x4;

// Problem dims
#define B_   32
#define CIN  32
#define V_   512
#define L_   64
#define COUT 64

// workspace float offsets
#define OFF_N1T  0          // 3*512*10 f32
#define OFF_T2   15360      // 3*512*10 f32
#define OFF_WTF  30720      // 128*64 f16 ([k][o])  = 4096 f32 slots
#define OFF_A1   34816      // 512*512 f32
#define OFF_A2   296960     // 512*512 f32
#define OFF_TMP  559104     // 512*512 f32 (T = A1*A2)
#define OFF_PST  821248     // 512*1536 f32  Pstack[v][w']: cols 0-511=P1, 512-1023=P2, 1024-1535=P3
#define OFF_PTF  1607680    // 3*512*512 f16 = 393216 f32 slots   PT[hop][w][v]
#define OFF_XTF  2000896    // chunk*32*64*512 f16, then Y f16

#define GLD_LDS16(gsrc, ldst) \
    __builtin_amdgcn_global_load_lds((const __attribute__((address_space(1))) void*)(gsrc), \
                                     (__attribute__((address_space(3))) void*)(ldst), 16, 0, 0)

// ---------------------------------------------------------------------------
// Kernel 1: node-vector hop transforms + mlp_w -> f16 [k][o] transpose
// ---------------------------------------------------------------------------
__global__ __launch_bounds__(256) void transform_kernel(
    const float* __restrict__ nv1, const float* __restrict__ nv2,
    const float* __restrict__ wtr, const float* __restrict__ btr,
    const float* __restrict__ mlpw, float* __restrict__ ws)
{
    float* n1t = ws + OFF_N1T;   // [3][512][10]
    float* t2  = ws + OFF_T2;    // [3][512][10]
    f16*   WTf = (f16*)(ws + OFF_WTF);  // [128][64]
    int t = threadIdx.x;
    for (int j = t; j < 5120; j += 256) {
        int v = j / 10, e = j % 10;
        n1t[j]        = nv1[j];
        t2[v*10 + e]  = nv2[e*512 + v];
    }
    for (int j = t; j < 8192; j += 256) {
        int k = j / 64, o = j % 64;
        WTf[j] = (f16)mlpw[o*128 + k];
    }
    __syncthreads();
    for (int h = 1; h <= 2; ++h) {
        const float* w = wtr + (h-1)*100;
        const float* b = btr + (h-1)*10;
        for (int j = t; j < 5120; j += 256) {
            int v = j / 10, e = j % 10;
            float s1 = b[e], s2 = b[e];
            #pragma unroll
            for (int f = 0; f < 10; ++f) {
                s1 += n1t[(h-1)*5120 + v*10 + f] * w[f*10 + e];
                s2 += t2 [(h-1)*5120 + v*10 + f] * w[f*10 + e];
            }
            n1t[h*5120 + j] = s1;
            t2 [h*5120 + j] = s2;
        }
        __syncthreads();
    }
}

// ---------------------------------------------------------------------------
// Kernel 2: adjacency rows: relu + row-softmax.  grid (512, 3)
// ---------------------------------------------------------------------------
__global__ __launch_bounds__(256) void adj_kernel(float* __restrict__ ws)
{
    int v = blockIdx.x, k = blockIdx.y;
    const float* n1v = ws + OFF_N1T + ((size_t)k*512 + v)*10;
    const float* t2b = ws + OFF_T2  + (size_t)k*5120;
    float n1r[10];
    #pragma unroll
    for (int e = 0; e < 10; ++e) n1r[e] = n1v[e];

    int t = threadIdx.x;
    float s[2];
    #pragma unroll
    for (int ii = 0; ii < 2; ++ii) {
        int w = t + ii*256;
        const float* t2w = t2b + w*10;
        float d = 0.f;
        #pragma unroll
        for (int e = 0; e < 10; ++e) d += n1r[e] * t2w[e];
        s[ii] = d > 0.f ? d : 0.f;
    }
    __shared__ float red[256];
    float m = fmaxf(s[0], s[1]);
    red[t] = m; __syncthreads();
    for (int off = 128; off > 0; off >>= 1) {
        if (t < off) red[t] = fmaxf(red[t], red[t+off]);
        __syncthreads();
    }
    float mx = red[0];
    __syncthreads();
    float e0 = expf(s[0]-mx), e1 = expf(s[1]-mx);
    red[t] = e0 + e1; __syncthreads();
    for (int off = 128; off > 0; off >>= 1) {
        if (t < off) red[t] += red[t+off];
        __syncthreads();
    }
    float inv = 1.f / red[0];

    float* dst;
    if (k == 0)      dst = ws + OFF_PST + (size_t)v*1536;
    else if (k == 1) dst = ws + OFF_A1  + (size_t)v*512;
    else             dst = ws + OFF_A2  + (size_t)v*512;
    dst[t]       = e0 * inv;
    dst[t + 256] = e1 * inv;
}

// ---------------------------------------------------------------------------
// Kernel 3: 512x512x512 fp32 matmuls for the hop chain.
//   chain2 (grid z=2): z0: P2 = A0*A1 ; z1: T = A1*A2   (independent)
//   chain1 (grid z=1): P3 = A0*T
// ---------------------------------------------------------------------------
__device__ __forceinline__ void chain_body(
    const float* __restrict__ A, int lda,
    const float* __restrict__ Bm, int ldb,
    float* __restrict__ C, int ldc)
{
    __shared__ float At[16][64];
    __shared__ float Bt[16][64];
    int tx = threadIdx.x % 16, ty = threadIdx.x / 16;
    int v0 = blockIdx.y * 64, w0 = blockIdx.x * 64;
    float acc[4][4] = {};
    for (int u0 = 0; u0 < 512; u0 += 16) {
        __syncthreads();
        #pragma unroll
        for (int i = 0; i < 4; ++i) {
            int j = threadIdx.x + i*256;
            int vv = j / 16, u = j % 16;
            At[u][vv] = A[(size_t)(v0+vv)*lda + u0 + u];
            int u2 = j / 64, ww = j % 64;
            Bt[u2][ww] = Bm[(size_t)(u0+u2)*ldb + w0 + ww];
        }
        __syncthreads();
        #pragma unroll
        for (int u = 0; u < 16; ++u) {
            float a[4], b[4];
            #pragma unroll
            for (int i = 0; i < 4; ++i) a[i] = At[u][ty*4+i];
            #pragma unroll
            for (int j = 0; j < 4; ++j) b[j] = Bt[u][tx*4+j];
            #pragma unroll
            for (int i = 0; i < 4; ++i)
                #pragma unroll
                for (int j = 0; j < 4; ++j)
                    acc[i][j] += a[i]*b[j];
        }
    }
    #pragma unroll
    for (int i = 0; i < 4; ++i)
        #pragma unroll
        for (int j = 0; j < 4; ++j)
            C[(size_t)(v0+ty*4+i)*ldc + w0+tx*4+j] = acc[i][j];
}

__global__ __launch_bounds__(256) void chain2_kernel(float* __restrict__ ws)
{
    if (blockIdx.z == 0)
        chain_body(ws+OFF_PST, 1536, ws+OFF_A1, 512, ws+OFF_PST+512, 1536);
    else
        chain_body(ws+OFF_A1, 512, ws+OFF_A2, 512, ws+OFF_TMP, 512);
}

__global__ __launch_bounds__(256) void chain1_kernel(float* __restrict__ ws)
{
    chain_body(ws+OFF_PST, 1536, ws+OFF_TMP, 512, ws+OFF_PST+1024, 1536);
}

// ---------------------------------------------------------------------------
// Kernel 3b: transpose + f16 convert of Pstack -> PT[hop][w][v]
//   grid (16, 16, 3), block 256
// ---------------------------------------------------------------------------
__global__ __launch_bounds__(256) void ptsplit_kernel(
    const float* __restrict__ Pst, f16* __restrict__ PTf)
{
    int h = blockIdx.z;
    int w0 = blockIdx.x * 32, v0 = blockIdx.y * 32;
    __shared__ float tile[32][33];
    int t = threadIdx.x;
    int tc = t & 31, tr = t >> 5;
    #pragma unroll
    for (int i = 0; i < 4; ++i) {
        int v = tr + i*8;
        tile[v][tc] = Pst[(size_t)(v0+v)*1536 + h*512 + w0 + tc];
    }
    __syncthreads();
    #pragma unroll
    for (int i = 0; i < 4; ++i) {
        int w = tr + i*8;
        PTf[((size_t)h*512 + w0 + w)*512 + v0 + tc] = (f16)tile[tc][w];
    }
}

// ---------------------------------------------------------------------------
// Kernel 3c: transpose + f16 convert of X chunk -> XT[cb][l][v]
//   grid (8, chunk*32), block 256
// ---------------------------------------------------------------------------
__global__ __launch_bounds__(256) void xtsplit_kernel(
    const float* __restrict__ x, f16* __restrict__ XTf, int n0)
{
    int cb = blockIdx.y;
    int v0 = blockIdx.x * 64;
    const float* Xb = x + ((size_t)n0*32 + cb)*(512*64);
    __shared__ float tile[64][65];
    int t = threadIdx.x;
    int tl4 = (t & 15) * 4, tv = t >> 4;
    #pragma unroll
    for (int i = 0; i < 4; ++i) {
        int v = tv + i*16;
        *(float4*)&tile[v][tl4] = *(const float4*)&Xb[(size_t)(v0+v)*64 + tl4];
    }
    __syncthreads();
    #pragma unroll
    for (int i = 0; i < 4; ++i) {
        int l = tv + i*16;
        f16x4 o;
        o[0] = (f16)tile[tl4+0][l];
        o[1] = (f16)tile[tl4+1][l];
        o[2] = (f16)tile[tl4+2][l];
        o[3] = (f16)tile[tl4+3][l];
        *(f16x4*)&XTf[((size_t)cb*64 + l)*512 + v0 + tl4] = o;
    }
}

// ---------------------------------------------------------------------------
// Kernel 4: single-f16 MFMA batched GEMM.
//   Y[cb][w'][l] = sum_v PT[w'][v] * XT[cb][l][v]
//   Block tile: M=128 (w'), N=128 (two cb's x 64 l), K-step 64.
//   grid (12, chunk*16): x -> hop=bx>>2, wtile=bx&3 ; block 256 = 4 waves.
// ---------------------------------------------------------------------------
__global__ __launch_bounds__(256, 4) void gemm_f16_kernel(
    const f16* __restrict__ PTf, const f16* __restrict__ XTf,
    f16* __restrict__ Yf)
{
    int bx = blockIdx.x;
    int by = blockIdx.y;
    int hop = bx >> 2, wt = bx & 3;
    const f16* Pg = PTf + ((size_t)hop*512 + wt*128)*512;
    const f16* Xg = XTf + (size_t)by*2*64*512;   // 128 B-rows

    __shared__ __align__(16) f16 Ah[128*64];   // 16 KB
    __shared__ __align__(16) f16 Bh[128*64];   // 16 KB

    int t = threadIdx.x;
    int wid = t >> 6, lane = t & 63;
    int wm0 = (wid >> 1) * 64;      // wave M offset (w')
    int wn0 = (wid & 1) * 64;       // wave N offset (cb_local*64 span)
    int lr = lane & 15;
    int lk = (lane >> 4) * 8;

    f32x4 acc[4][4];
    #pragma unroll
    for (int i = 0; i < 4; ++i)
        #pragma unroll
        for (int j = 0; j < 4; ++j)
            acc[i][j] = (f32x4){0.f, 0.f, 0.f, 0.f};

    for (int v0 = 0; v0 < 512; v0 += 64) {
        __syncthreads();
        // stage A and B (each 128 rows x 64 f16) via async global->LDS, 16B/lane
        #pragma unroll
        for (int i = 0; i < 4; ++i) {
            int ch = wid*4 + i;                 // 16 chunks of 512 f16 each
            int e  = ch*512 + lane*8;
            int m  = e >> 6, c = e & 63;
            GLD_LDS16(Pg + (size_t)m*512 + v0 + c, Ah + ch*512);
            GLD_LDS16(Xg + (size_t)m*512 + v0 + c, Bh + ch*512);
        }
        __syncthreads();
        #pragma unroll
        for (int kk = 0; kk < 2; ++kk) {
            int ko = kk*32 + lk;
            f16x8 b[4];
            #pragma unroll
            for (int nf = 0; nf < 4; ++nf)
                b[nf] = *(const f16x8*)&Bh[(wn0 + nf*16 + lr)*64 + ko];
            #pragma unroll
            for (int mf = 0; mf < 4; ++mf) {
                f16x8 a = *(const f16x8*)&Ah[(wm0 + mf*16 + lr)*64 + ko];
                #pragma unroll
                for (int nf = 0; nf < 4; ++nf)
                    acc[mf][nf] = __builtin_amdgcn_mfma_f32_16x16x32_f16(a, b[nf], acc[mf][nf], 0, 0, 0);
            }
        }
    }
    // Epilogue: C row = wm0 + mf*16 + (lane>>4)*4 + r ; col n = wn0 + nf*16 + lr
    int orow = wm0 + (lane >> 4) * 4;
    size_t wbase = (size_t)hop*512 + wt*128;
    #pragma unroll
    for (int mf = 0; mf < 4; ++mf) {
        #pragma unroll
        for (int nf = 0; nf < 4; ++nf) {
            int n = wn0 + nf*16 + lr;
            int cbl = n >> 6, l = n & 63;
            size_t rb = ((size_t)(by*2 + cbl)*1536 + wbase + orow + mf*16);
            #pragma unroll
            for (int r = 0; r < 4; ++r)
                Yf[(rb + r)*64 + l] = (f16)acc[mf][nf][r];
        }
    }
}

// ---------------------------------------------------------------------------
// Kernel 5: combine / 1x1 conv.  grid (512 w, chunkN).  block 256.
//   out[n,o,w,l] = b[o] + sum_c W[o,c]x + W[o,32+c]Y1[l] + W[o,64+c]Y2[l-1] + W[o,96+c]Y3[l-3]
// ---------------------------------------------------------------------------
__global__ __launch_bounds__(256, 3) void combine_kernel(
    const float* __restrict__ x, const f16* __restrict__ Yf,
    const f16* __restrict__ WTf, const float* __restrict__ bias,
    float* __restrict__ out, int n0)
{
    int w  = blockIdx.x;
    int cn = blockIdx.y;
    int n  = n0 + cn;
    __shared__ __align__(16) float Hs[128*64];   // 32 KB
    __shared__ __align__(16) f16   Ws[128*64];   // 16 KB  [k][o]
    int t = threadIdx.x;

    #pragma unroll
    for (int i = 0; i < 4; ++i) {
        int j = (t + i*256)*8;
        *(f16x8*)&Ws[j] = *(const f16x8*)&WTf[j];
    }
    // rows 0..31 = x (fp32 loads)
    #pragma unroll
    for (int i = 0; i < 2; ++i) {
        int j = t + i*256;
        int c = j / 16, lq = j % 16;
        *(float4*)&Hs[c*64 + lq*4] =
            *(const float4*)&x[(((size_t)n*32 + c)*512 + w)*64 + lq*4];
    }
    // rows 32..63 = Y1 (f16x8 loads)
    {
        int c = t >> 3, lq = t & 7;
        f16x8 yv = *(const f16x8*)&Yf[(((size_t)cn*32 + c)*1536 + w)*64 + lq*8];
        float4 lo = {(float)yv[0], (float)yv[1], (float)yv[2], (float)yv[3]};
        float4 hi = {(float)yv[4], (float)yv[5], (float)yv[6], (float)yv[7]};
        *(float4*)&Hs[(32+c)*64 + lq*8]     = lo;
        *(float4*)&Hs[(32+c)*64 + lq*8 + 4] = hi;
    }
    // rows 64..95 = Y2 shifted by 1 ; rows 96..127 = Y3 shifted by 3
    #pragma unroll
    for (int i = 0; i < 8; ++i) {
        int j = t + i*256;
        int c = j / 64, l = j % 64;
        float v2 = (l >= 1) ? (float)Yf[(((size_t)cn*32 + c)*1536 + 512  + w)*64 + (l-1)] : 0.f;
        float v3 = (l >= 3) ? (float)Yf[(((size_t)cn*32 + c)*1536 + 1024 + w)*64 + (l-3)] : 0.f;
        Hs[(64+c)*64 + l] = v2;
        Hs[(96+c)*64 + l] = v3;
    }
    __syncthreads();

    int lg = t % 16, og = t / 16;
    int o0 = og*4, l0 = lg*4;
    float acc[4][4];
    #pragma unroll
    for (int i = 0; i < 4; ++i) {
        float bv = bias[o0+i];
        #pragma unroll
        for (int j = 0; j < 4; ++j) acc[i][j] = bv;
    }
    #pragma unroll 4
    for (int k = 0; k < 128; ++k) {
        f16x4 wv = *(const f16x4*)&Ws[k*64 + o0];
        float4 hv = *(float4*)&Hs[k*64 + l0];
        float wa[4] = {(float)wv[0], (float)wv[1], (float)wv[2], (float)wv[3]};
        float ha[4] = {hv.x, hv.y, hv.z, hv.w};
        #pragma unroll
        for (int i = 0; i < 4; ++i)
            #pragma unroll
            for (int j = 0; j < 4; ++j)
                acc[i][j] += wa[i]*ha[j];
    }
    #pragma unroll
    for (int i = 0; i < 4; ++i) {
        float4 o = {acc[i][0], acc[i][1], acc[i][2], acc[i][3]};
        *(float4*)&out[(((size_t)n*64 + o0+i)*512 + w)*64 + l0] = o;
    }
}

// ---------------------------------------------------------------------------
extern "C" void kernel_launch(void* const* d_in, const int* in_sizes, int n_in,
                              void* d_out, int out_size, void* d_ws, size_t ws_size,
                              hipStream_t stream) {
    const float* x    = (const float*)d_in[0];
    const float* nv1  = (const float*)d_in[1];
    const float* nv2  = (const float*)d_in[2];
    const float* wtr  = (const float*)d_in[3];
    const float* btr  = (const float*)d_in[4];
    const float* mlpw = (const float*)d_in[5];
    const float* mlpb = (const float*)d_in[6];
    float* out = (float*)d_out;
    float* ws  = (float*)d_ws;

    transform_kernel<<<1, 256, 0, stream>>>(nv1, nv2, wtr, btr, mlpw, ws);
    adj_kernel<<<dim3(512, 3), 256, 0, stream>>>(ws);
    // P2 = A0*A1 and T = A1*A2 in one launch; then P3 = A0*T
    chain2_kernel<<<dim3(8, 8, 2), 256, 0, stream>>>(ws);
    chain1_kernel<<<dim3(8, 8), 256, 0, stream>>>(ws);

    f16* PTf = (f16*)(ws + OFF_PTF);
    ptsplit_kernel<<<dim3(16, 16, 3), 256, 0, stream>>>(ws + OFF_PST, PTf);

    // chunk selection: floats needed = OFF_XTF + chunk*(524288 XT + 1572864 Y)
    size_t ws_f = ws_size / 4;
    int chunk = 32;
    while (chunk > 1 && (size_t)OFF_XTF + (size_t)chunk*2097152ull > ws_f) chunk >>= 1;

    f16* XTf = (f16*)(ws + OFF_XTF);
    f16* Yf  = (f16*)(ws + OFF_XTF + (size_t)chunk*524288);

    for (int n0 = 0; n0 < 32; n0 += chunk) {
        xtsplit_kernel<<<dim3(8, chunk*32), 256, 0, stream>>>(x, XTf, n0);
        gemm_f16_kernel<<<dim3(12, chunk*16), 256, 0, stream>>>(PTf, XTf, Yf);
        combine_kernel<<<dim3(512, chunk), 256, 0, stream>>>(x, Yf, (f16*)(ws + OFF_WTF), mlpb, out, n0);
    }
}